// Round 1
// baseline (579.969 us; speedup 1.0000x reference)
//
#include <hip/hip_runtime.h>

// Fused causal self-attention block for B=4, S=2048, D=1024, H=16, dk=64.
// Pipeline: cast/transpose -> QKV GEMM (bf16 MFMA) -> flash attention ->
//           output GEMM + residual -> LayerNorm (in-place on d_out).

typedef __attribute__((ext_vector_type(8))) short short8;
typedef __attribute__((ext_vector_type(4))) float f32x4;

#define S_LEN 2048
#define NH 16
#define DK 64
#define DMODEL 1024

__device__ inline unsigned short f2bf(float f) {
    unsigned int u = __builtin_bit_cast(unsigned int, f);
    unsigned int r = (u + 0x7fffu + ((u >> 16) & 1u)) >> 16;  // RNE
    return (unsigned short)r;
}

// ---------------- cast x (fp32 -> bf16), vectorized ----------------
__global__ __launch_bounds__(256) void cast_x_kernel(const float* __restrict__ x,
                                                     unsigned short* __restrict__ xb,
                                                     int n4) {
    int i = blockIdx.x * 256 + threadIdx.x;
    if (i >= n4) return;
    float4 v = reinterpret_cast<const float4*>(x)[i];
    ushort4 o;
    o.x = f2bf(v.x); o.y = f2bf(v.y); o.z = f2bf(v.z); o.w = f2bf(v.w);
    reinterpret_cast<ushort4*>(xb)[i] = o;
}

// ---------------- 1024x1024 transpose fp32 -> bf16 (B^T layout for GEMM) ----
__global__ __launch_bounds__(256) void transpose1024_kernel(const float* __restrict__ in,
                                                            unsigned short* __restrict__ out) {
    int i = blockIdx.x;                      // out row
    int j = blockIdx.y * 256 + threadIdx.x;  // out col (coalesced write)
    out[i * 1024 + j] = f2bf(in[j * 1024 + i]);
}

// ---------------- GEMM  C[M,N] = A[M,K] * Bt[N,K]^T  (bf16 in, fp32 acc) ----
// 128x128 tile, 4 waves, each wave 64x64 via 4x4 frags of 16x16x32 MFMA.
// MODE 0: QKV epilogue (scatter to q/k/v [B,H,S,dk] bf16, +bias)
// MODE 1: attn-out epilogue (out = acc + bo + x residual, fp32)
template <int MODE>
__global__ __launch_bounds__(256) void gemm_bt_kernel(
    const unsigned short* __restrict__ A, const unsigned short* __restrict__ Bt,
    int M, int N, int K,
    unsigned short* __restrict__ qb, unsigned short* __restrict__ kb,
    unsigned short* __restrict__ vb,
    const float* __restrict__ bq, const float* __restrict__ bk,
    const float* __restrict__ bv,
    const float* __restrict__ xres, const float* __restrict__ bo,
    float* __restrict__ out) {
    __shared__ unsigned short Al[128][72];  // +8 pad: 144B row stride -> free 2-way
    __shared__ unsigned short Bl[128][72];
    int tid = threadIdx.x;
    int m0 = blockIdx.y * 128, n0 = blockIdx.x * 128;
    int w = tid >> 6, l = tid & 63, g = l >> 4, lr = l & 15;
    int wr = (w >> 1) * 64, wc = (w & 1) * 64;
    f32x4 acc[4][4];
    for (int i = 0; i < 4; ++i)
        for (int j = 0; j < 4; ++j)
            for (int e = 0; e < 4; ++e) acc[i][j][e] = 0.0f;

    for (int k0 = 0; k0 < K; k0 += 64) {
        for (int i = 0; i < 4; ++i) {
            int c = tid + i * 256;
            int row = c >> 3, c8 = (c & 7) * 8;
            *reinterpret_cast<uint4*>(&Al[row][c8]) =
                *reinterpret_cast<const uint4*>(&A[(size_t)(m0 + row) * K + k0 + c8]);
            *reinterpret_cast<uint4*>(&Bl[row][c8]) =
                *reinterpret_cast<const uint4*>(&Bt[(size_t)(n0 + row) * K + k0 + c8]);
        }
        __syncthreads();
        for (int kk = 0; kk < 64; kk += 32) {
            short8 af[4], bf[4];
            for (int mi = 0; mi < 4; ++mi)
                af[mi] = *reinterpret_cast<const short8*>(&Al[wr + mi * 16 + lr][kk + g * 8]);
            for (int ni = 0; ni < 4; ++ni)
                bf[ni] = *reinterpret_cast<const short8*>(&Bl[wc + ni * 16 + lr][kk + g * 8]);
            for (int mi = 0; mi < 4; ++mi)
                for (int ni = 0; ni < 4; ++ni)
                    acc[mi][ni] = __builtin_amdgcn_mfma_f32_16x16x32_bf16(
                        af[mi], bf[ni], acc[mi][ni], 0, 0, 0);
        }
        __syncthreads();
    }
    // Epilogue. D layout: row=(l>>4)*4+r, col=l&15 (m89-verified).
    for (int mi = 0; mi < 4; ++mi) {
        for (int ni = 0; ni < 4; ++ni) {
            int col = n0 + wc + ni * 16 + lr;
            for (int r = 0; r < 4; ++r) {
                int m = m0 + wr + mi * 16 + g * 4 + r;
                float val = acc[mi][ni][r];
                if (MODE == 0) {
                    int sel = col >> 10, nn = col & 1023;
                    int hh = nn >> 6, kk2 = nn & 63;
                    int bb2 = m >> 11, ss2 = m & 2047;
                    size_t dst = (((size_t)bb2 * NH + hh) * S_LEN + ss2) * DK + kk2;
                    if (sel == 0)      qb[dst] = f2bf(val + bq[nn]);
                    else if (sel == 1) kb[dst] = f2bf(val + bk[nn]);
                    else               vb[dst] = f2bf(val + bv[nn]);
                } else {
                    float v2 = val + bo[col] + xres[(size_t)m * DMODEL + col];
                    out[(size_t)m * DMODEL + col] = v2;
                }
            }
        }
    }
}

// ---------------- flash attention, causal ----------------
// Block: one (b,h), 64 Q rows, 4 waves x 16 rows. KV tiles of 64.
__global__ __launch_bounds__(256) void attn_kernel(const unsigned short* __restrict__ qb,
                                                   const unsigned short* __restrict__ kb,
                                                   const unsigned short* __restrict__ vb,
                                                   unsigned short* __restrict__ ctx) {
    __shared__ unsigned short Ql[64][72], Kl[64][72], Vt[64][72], Pl[64][72];
    int qt = blockIdx.x, h = blockIdx.y, b = blockIdx.z;
    int q0 = qt * 64;
    size_t base = ((size_t)b * NH + h) * S_LEN * DK;
    int tid = threadIdx.x, w = tid >> 6, l = tid & 63, g = l >> 4, lr = l & 15;

    for (int i = 0; i < 2; ++i) {
        int c = tid + i * 256;
        int row = c >> 3, c8 = (c & 7) * 8;
        *reinterpret_cast<uint4*>(&Ql[row][c8]) =
            *reinterpret_cast<const uint4*>(&qb[base + (size_t)(q0 + row) * DK + c8]);
    }
    __syncthreads();
    short8 qf[2];
    qf[0] = *reinterpret_cast<const short8*>(&Ql[w * 16 + lr][g * 8]);
    qf[1] = *reinterpret_cast<const short8*>(&Ql[w * 16 + lr][32 + g * 8]);

    f32x4 ctxa[4];
    for (int f = 0; f < 4; ++f)
        for (int e = 0; e < 4; ++e) ctxa[f][e] = 0.0f;
    float m_r[4], l_r[4];
    for (int r = 0; r < 4; ++r) { m_r[r] = -3e38f; l_r[r] = 0.f; }

    for (int t = 0; t <= qt; ++t) {
        int kv0 = t * 64;
        __syncthreads();  // protect Kl/Vt from overwrite while prev tile in use
        for (int i = 0; i < 2; ++i) {
            int c = tid + i * 256;
            int row = c >> 3, c8 = (c & 7) * 8;
            *reinterpret_cast<uint4*>(&Kl[row][c8]) =
                *reinterpret_cast<const uint4*>(&kb[base + (size_t)(kv0 + row) * DK + c8]);
            uint4 vq = *reinterpret_cast<const uint4*>(&vb[base + (size_t)(kv0 + row) * DK + c8]);
            const unsigned short* vp = reinterpret_cast<const unsigned short*>(&vq);
            for (int j = 0; j < 8; ++j) Vt[c8 + j][row] = vp[j];  // V^T for PV B-frag
        }
        __syncthreads();

        // S = Q K^T / sqrt(dk)
        f32x4 sc[4];
        for (int f = 0; f < 4; ++f)
            for (int e = 0; e < 4; ++e) sc[f][e] = 0.0f;
        for (int ks = 0; ks < 2; ++ks)
            for (int f = 0; f < 4; ++f) {
                short8 bbf = *reinterpret_cast<const short8*>(&Kl[f * 16 + lr][ks * 32 + g * 8]);
                sc[f] = __builtin_amdgcn_mfma_f32_16x16x32_bf16(qf[ks], bbf, sc[f], 0, 0, 0);
            }
        for (int f = 0; f < 4; ++f)
            for (int r = 0; r < 4; ++r) sc[f][r] *= 0.125f;
        if (t == qt) {  // diagonal tile: causal mask
            for (int f = 0; f < 4; ++f)
                for (int r = 0; r < 4; ++r) {
                    int colg = kv0 + f * 16 + lr;
                    int rowg = q0 + w * 16 + g * 4 + r;
                    if (colg > rowg) sc[f][r] = -3e38f;
                }
        }
        // online softmax; row lives in 16-lane group (cols) x 4 frags
        float tm[4], alpha[4], ts[4];
        for (int r = 0; r < 4; ++r)
            tm[r] = fmaxf(fmaxf(sc[0][r], sc[1][r]), fmaxf(sc[2][r], sc[3][r]));
        for (int mk = 1; mk < 16; mk <<= 1)
            for (int r = 0; r < 4; ++r) tm[r] = fmaxf(tm[r], __shfl_xor(tm[r], mk));
        for (int r = 0; r < 4; ++r) {
            float mn = fmaxf(m_r[r], tm[r]);
            alpha[r] = __expf(m_r[r] - mn);
            m_r[r] = mn;
            l_r[r] *= alpha[r];
            ts[r] = 0.f;
        }
        for (int f = 0; f < 4; ++f)
            for (int r = 0; r < 4; ++r) ctxa[f][r] *= alpha[r];
        for (int f = 0; f < 4; ++f)
            for (int r = 0; r < 4; ++r) {
                float p = __expf(sc[f][r] - m_r[r]);
                ts[r] += p;
                Pl[w * 16 + g * 4 + r][f * 16 + lr] = f2bf(p);
            }
        for (int mk = 1; mk < 16; mk <<= 1)
            for (int r = 0; r < 4; ++r) ts[r] += __shfl_xor(ts[r], mk);
        for (int r = 0; r < 4; ++r) l_r[r] += ts[r];
        __syncthreads();  // Pl visible for A-frag reads
        // ctx += P V
        for (int ks = 0; ks < 2; ++ks) {
            short8 pa = *reinterpret_cast<const short8*>(&Pl[w * 16 + lr][ks * 32 + g * 8]);
            for (int f = 0; f < 4; ++f) {
                short8 bv2 = *reinterpret_cast<const short8*>(&Vt[f * 16 + lr][ks * 32 + g * 8]);
                ctxa[f] = __builtin_amdgcn_mfma_f32_16x16x32_bf16(pa, bv2, ctxa[f], 0, 0, 0);
            }
        }
    }
    // write ctx [B,S,H,dk] bf16
    for (int f = 0; f < 4; ++f)
        for (int r = 0; r < 4; ++r) {
            int s = q0 + w * 16 + g * 4 + r;
            int d = f * 16 + lr;
            ctx[(((size_t)b * S_LEN + s) * NH + h) * DK + d] = f2bf(ctxa[f][r] / l_r[r]);
        }
}

// ---------------- LayerNorm in-place on d_out ----------------
__global__ __launch_bounds__(256) void ln_kernel(float* __restrict__ y,
                                                 const float* __restrict__ gamma,
                                                 const float* __restrict__ beta) {
    int row = blockIdx.x, tid = threadIdx.x;
    float4 v = reinterpret_cast<const float4*>(y + (size_t)row * DMODEL)[tid];
    float s = v.x + v.y + v.z + v.w;
    float q = v.x * v.x + v.y * v.y + v.z * v.z + v.w * v.w;
    for (int off = 32; off >= 1; off >>= 1) {
        s += __shfl_down(s, off);
        q += __shfl_down(q, off);
    }
    __shared__ float ss[4], sq[4];
    int w = tid >> 6, l = tid & 63;
    if (l == 0) { ss[w] = s; sq[w] = q; }
    __syncthreads();
    s = ss[0] + ss[1] + ss[2] + ss[3];
    q = sq[0] + sq[1] + sq[2] + sq[3];
    float mu = s * (1.0f / 1024.0f);
    float var = q * (1.0f / 1024.0f) - mu * mu;
    float inv = rsqrtf(var + 1e-6f);
    float4 g4 = reinterpret_cast<const float4*>(gamma)[tid];
    float4 b4 = reinterpret_cast<const float4*>(beta)[tid];
    float4 o;
    o.x = (v.x - mu) * inv * g4.x + b4.x;
    o.y = (v.y - mu) * inv * g4.y + b4.y;
    o.z = (v.z - mu) * inv * g4.z + b4.z;
    o.w = (v.w - mu) * inv * g4.w + b4.w;
    reinterpret_cast<float4*>(y + (size_t)row * DMODEL)[tid] = o;
}

extern "C" void kernel_launch(void* const* d_in, const int* in_sizes, int n_in,
                              void* d_out, int out_size, void* d_ws, size_t ws_size,
                              hipStream_t stream) {
    const float* x     = (const float*)d_in[0];
    const float* Wq    = (const float*)d_in[1];
    const float* bq    = (const float*)d_in[2];
    const float* Wk    = (const float*)d_in[3];
    const float* bk    = (const float*)d_in[4];
    const float* Wv    = (const float*)d_in[5];
    const float* bv    = (const float*)d_in[6];
    const float* Wo    = (const float*)d_in[7];
    const float* bo    = (const float*)d_in[8];
    const float* gamma = (const float*)d_in[9];
    const float* beta  = (const float*)d_in[10];
    float* out = (float*)d_out;
    char* ws = (char*)d_ws;
    // ws layout (72 MB total):
    unsigned short* xbf   = (unsigned short*)(ws);              // 16 MB (reused as ctx)
    unsigned short* wqkvT = (unsigned short*)(ws + 16777216);   // 6 MB  [3072][1024]
    unsigned short* woT   = (unsigned short*)(ws + 23068672);   // 2 MB  [1024][1024]
    unsigned short* qbuf  = (unsigned short*)(ws + 25165824);   // 16 MB [B,H,S,dk]
    unsigned short* kbuf  = (unsigned short*)(ws + 41943040);   // 16 MB
    unsigned short* vbuf  = (unsigned short*)(ws + 58720256);   // 16 MB
    unsigned short* ctx   = xbf;  // xbf dead after QKV GEMM

    cast_x_kernel<<<8192, 256, 0, stream>>>(x, xbf, 2097152);
    dim3 tg(1024, 4);
    transpose1024_kernel<<<tg, 256, 0, stream>>>(Wq, wqkvT);
    transpose1024_kernel<<<tg, 256, 0, stream>>>(Wk, wqkvT + 1048576);
    transpose1024_kernel<<<tg, 256, 0, stream>>>(Wv, wqkvT + 2097152);
    transpose1024_kernel<<<tg, 256, 0, stream>>>(Wo, woT);

    dim3 g1(24, 64);  // N/128, M/128
    gemm_bt_kernel<0><<<g1, 256, 0, stream>>>(xbf, wqkvT, 8192, 3072, 1024,
                                              qbuf, kbuf, vbuf, bq, bk, bv,
                                              nullptr, nullptr, nullptr);
    dim3 ga(32, 16, 4);  // S/64, H, B
    attn_kernel<<<ga, 256, 0, stream>>>(qbuf, kbuf, vbuf, ctx);

    dim3 g2(8, 64);
    gemm_bt_kernel<1><<<g2, 256, 0, stream>>>(ctx, woT, 8192, 1024, 1024,
                                              nullptr, nullptr, nullptr,
                                              nullptr, nullptr, nullptr,
                                              x, bo, out);
    ln_kernel<<<8192, 256, 0, stream>>>(out, gamma, beta);
}